// Round 6
// baseline (280.610 us; speedup 1.0000x reference)
//
#include <hip/hip_runtime.h>
#include <hip/hip_bf16.h>

#define LOG2E 1.4426950408889634f

typedef __bf16 bf16x8 __attribute__((ext_vector_type(8)));
typedef __bf16 bf16x4 __attribute__((ext_vector_type(4)));
typedef __bf16 bf16x2 __attribute__((ext_vector_type(2)));
typedef float  floatx4 __attribute__((ext_vector_type(4)));

__device__ __forceinline__ floatx4 mfma16(bf16x8 a, bf16x8 b, floatx4 c) {
  return __builtin_amdgcn_mfma_f32_16x16x32_bf16(a, b, c, 0, 0, 0);
}

// async global->LDS, 16B per lane. Dest = wave-uniform base + lane*16.
__device__ __forceinline__ void load_lds16(const __bf16* g, __bf16* l) {
  __builtin_amdgcn_global_load_lds(
      (const __attribute__((address_space(1))) void*)g,
      (__attribute__((address_space(3))) void*)l, 16, 0, 0);
}

__device__ __forceinline__ unsigned pack_bf16(float a, float b) {
  bf16x2 t = {(__bf16)a, (__bf16)b};
  return *(unsigned*)&t;
}

// ---------------------------------------------------------------------------
// Fold LoRA into weights, emit W_eff^T bf16 [ncols][1024].
// La row (stride-8, contiguous) cached in regs; Lb tile staged via LDS.
// ---------------------------------------------------------------------------
__global__ __launch_bounds__(256)
void fold_wt(const float* __restrict__ W, const float* __restrict__ La,
             const float* __restrict__ Lb, __bf16* __restrict__ WT, int ncols) {
  __shared__ float tile[64][65];
  __shared__ float sLb[8][64];
  const int kt = blockIdx.y * 64, nt = blockIdx.x * 64;
  const int tid = threadIdx.x;
  const int tx = tid & 63, ty = tid >> 6;

  // per-thread La row for k = kt+tx (8 contiguous floats)
  float rLa[8];
  *(float4*)&rLa[0] = *(const float4*)(La + (size_t)(kt + tx) * 8);
  *(float4*)&rLa[4] = *(const float4*)(La + (size_t)(kt + tx) * 8 + 4);

  // Lb tile: 8 rows x 64 cols
#pragma unroll
  for (int rep = 0; rep < 2; rep++) {
    int idx = tid + rep * 256;
    sLb[idx >> 6][idx & 63] = Lb[(size_t)(idx >> 6) * ncols + nt + (idx & 63)];
  }
#pragma unroll
  for (int rep = 0; rep < 16; rep++) {
    int i = rep * 4 + ty;
    tile[i][tx] = W[(size_t)(kt + i) * ncols + nt + tx];
  }
  __syncthreads();
#pragma unroll
  for (int rep = 0; rep < 16; rep++) {
    int i = rep * 4 + ty;
    int n = nt + i, k = kt + tx;
    float acc = tile[tx][i];
#pragma unroll
    for (int r = 0; r < 8; r++)
      acc += 2.0f * rLa[r] * sLb[r][i];  // LORA_SCALING = 2
    WT[(size_t)n * 1024 + k] = (__bf16)acc;
  }
}

__global__ __launch_bounds__(256)
void cast_x(const float* __restrict__ x, __bf16* __restrict__ o) {
  int i = blockIdx.x * 256 + threadIdx.x;
  float4 v = ((const float4*)x)[i];
  bf16x4 r = {(__bf16)v.x, (__bf16)v.y, (__bf16)v.z, (__bf16)v.w};
  ((bf16x4*)o)[i] = r;
}

// ---------------------------------------------------------------------------
// Fused QKV projection, swapped orientation: D[p][s] = sum_k WT[p][k] X[s][k].
// 128x128 tiles, BK=64, global_load_lds staging, XOR-swizzled LDS.
// ---------------------------------------------------------------------------
__global__ __launch_bounds__(256)
void gemm_qkv(const __bf16* __restrict__ WT, const __bf16* __restrict__ X,
              const float* __restrict__ bias, __bf16* __restrict__ qk,
              __bf16* __restrict__ vtb) {
  const int K = 1024;
  __shared__ alignas(16) __bf16 As[128 * 64];
  __shared__ alignas(16) __bf16 Bs[128 * 64];
  const int tid = threadIdx.x;
  const int wave = tid >> 6, lane = tid & 63;
  const int wm = wave >> 1, wn = wave & 1;
  const int quad = lane >> 4, l15 = lane & 15;
  const int p0 = blockIdx.y * 128, s0 = blockIdx.x * 128;
  const int srow8 = lane >> 3, sc8 = lane & 7;
  const int sswz = sc8 ^ srow8;

  floatx4 acc[4][4] = {};

  for (int kb = 0; kb < K; kb += 64) {
    __syncthreads();
#pragma unroll
    for (int t = 0; t < 4; t++) {
      int rbase = (wave * 4 + t) * 8;
      int row = rbase + srow8;
      load_lds16(WT + (size_t)(p0 + row) * K + kb + sswz * 8, As + rbase * 64);
      load_lds16(X + (size_t)(s0 + row) * K + kb + sswz * 8, Bs + rbase * 64);
    }
    __syncthreads();
#pragma unroll
    for (int ks = 0; ks < 2; ks++) {
      bf16x8 af[4], bfv[4];
#pragma unroll
      for (int t = 0; t < 4; t++) {
        int ra = wm * 64 + t * 16 + l15;
        int rb = wn * 64 + t * 16 + l15;
        int ch = (ks * 4 + quad) ^ (l15 & 7);
        af[t]  = *(const bf16x8*)(As + ra * 64 + ch * 8);
        bfv[t] = *(const bf16x8*)(Bs + rb * 64 + ch * 8);
      }
#pragma unroll
      for (int mi = 0; mi < 4; mi++)
#pragma unroll
        for (int ni = 0; ni < 4; ni++)
          acc[mi][ni] = mfma16(af[mi], bfv[ni], acc[mi][ni]);
    }
  }

#pragma unroll
  for (int mi = 0; mi < 4; mi++) {
#pragma unroll
    for (int ni = 0; ni < 4; ni++) {
      int pb = p0 + wm * 64 + mi * 16 + quad * 4;  // channel base (mult of 4)
      int s  = s0 + wn * 64 + ni * 16 + l15;       // token
      int b = s >> 11, s2 = s & 2047;
      if (p0 < 2048) {  // q/k: uniform per block
        int part = pb >> 10, h = (pb & 1023) >> 6, dhb = pb & 63;
        bf16x4 o = {(__bf16)(acc[mi][ni][0] + bias[pb]),
                    (__bf16)(acc[mi][ni][1] + bias[pb + 1]),
                    (__bf16)(acc[mi][ni][2] + bias[pb + 2]),
                    (__bf16)(acc[mi][ni][3] + bias[pb + 3])};
        *(bf16x4*)(qk + (size_t)part * 4194304 +
                   ((size_t)((b * 16 + h) * 2048 + s2)) * 64 + dhb) = o;
      } else {  // v -> v^T
        int h = (pb & 1023) >> 6, dhb = pb & 63;
#pragma unroll
        for (int r = 0; r < 4; r++)
          vtb[((size_t)((b * 16 + h) * 64 + dhb + r)) * 2048 + s2] =
              (__bf16)(acc[mi][ni][r] + bias[pb + r]);
      }
    }
  }
}

// ---------------------------------------------------------------------------
// Output projection, 64x128 tile: grid (8, 64) = 512 blocks.  fp32 out + bias.
// ---------------------------------------------------------------------------
__global__ __launch_bounds__(256)
void gemm_proj(const __bf16* __restrict__ A, const __bf16* __restrict__ BT,
               const float* __restrict__ bias, float* __restrict__ Cout, int N) {
  const int K = 1024;
  __shared__ alignas(16) __bf16 As[64 * 64];
  __shared__ alignas(16) __bf16 Bs[128 * 64];
  const int tid = threadIdx.x;
  const int wave = tid >> 6, lane = tid & 63;
  const int wm = wave >> 1, wn = wave & 1;
  const int quad = lane >> 4, l15 = lane & 15;
  const int m0 = blockIdx.y * 64, n0 = blockIdx.x * 128;
  const int srow8 = lane >> 3, sc8 = lane & 7;
  const int sswz = sc8 ^ srow8;

  floatx4 acc[2][4] = {};

  for (int kb = 0; kb < K; kb += 64) {
    __syncthreads();
#pragma unroll
    for (int t = 0; t < 2; t++) {
      int rbase = (wave * 2 + t) * 8;
      load_lds16(A + (size_t)(m0 + rbase + srow8) * K + kb + sswz * 8,
                 As + rbase * 64);
    }
#pragma unroll
    for (int t = 0; t < 4; t++) {
      int rbase = (wave * 4 + t) * 8;
      load_lds16(BT + (size_t)(n0 + rbase + srow8) * K + kb + sswz * 8,
                 Bs + rbase * 64);
    }
    __syncthreads();
#pragma unroll
    for (int ks = 0; ks < 2; ks++) {
      bf16x8 af[2], bfv[4];
      int ch = (ks * 4 + quad) ^ (l15 & 7);
#pragma unroll
      for (int t = 0; t < 2; t++)
        af[t] = *(const bf16x8*)(As + (wm * 32 + t * 16 + l15) * 64 + ch * 8);
#pragma unroll
      for (int t = 0; t < 4; t++)
        bfv[t] = *(const bf16x8*)(Bs + (wn * 64 + t * 16 + l15) * 64 + ch * 8);
#pragma unroll
      for (int mi = 0; mi < 2; mi++)
#pragma unroll
        for (int ni = 0; ni < 4; ni++)
          acc[mi][ni] = mfma16(af[mi], bfv[ni], acc[mi][ni]);
    }
  }

#pragma unroll
  for (int mi = 0; mi < 2; mi++)
#pragma unroll
    for (int ni = 0; ni < 4; ni++) {
      int n = n0 + wn * 64 + ni * 16 + l15;
#pragma unroll
      for (int r = 0; r < 4; r++) {
        int m = m0 + wm * 32 + mi * 16 + quad * 4 + r;
        Cout[(size_t)m * N + n] = acc[mi][ni][r] + bias[n];
      }
    }
}

// ---------------------------------------------------------------------------
// Barrier-free, LDS-free causal flash attention v5.
// One wave per 16-q strip (4096 waves), 64-key chunks, K-frag register
// double-buffer (prefetch c+1 during softmax of c), V issued at chunk top.
// S^T = K·Q^T: col(l15)=q, row(quad*4+r)=key -> softmax in-register.
// P C-layout -> A-layout via cross-lane shuffles (16/chunk).
// Masks BEFORE scale like the reference: masked -> -1e9/8 = -1.25e8.
// ---------------------------------------------------------------------------
__global__ __launch_bounds__(64)
void flash_attn(const __bf16* __restrict__ q, const __bf16* __restrict__ k,
                const __bf16* __restrict__ vt, const int* __restrict__ amask,
                __bf16* __restrict__ ctx) {
  const int S = 2048;
  const int t = blockIdx.x;
  const int bh = t & 31;
  const int j = 127 - (t >> 5);     // strip index, heaviest first
  const int b = bh >> 4, h = bh & 15;
  const int lane = threadIdx.x;
  const int quad = lane >> 4, l15 = lane & 15;
  const int q0 = j * 16;

  const __bf16* qp  = q  + (size_t)bh * S * 64;
  const __bf16* kp0 = k  + (size_t)bh * S * 64;
  const __bf16* vp0 = vt + (size_t)bh * 64 * S;

  bf16x8 qf[2];  // [ks]
#pragma unroll
  for (int ks = 0; ks < 2; ks++)
    qf[ks] = *(const bf16x8*)(qp + (size_t)(q0 + l15) * 64 + ks * 32 + quad * 8);

  float mrun = -3.0e38f, lrun = 0.0f;
  floatx4 oacc[4] = {};
  const int nch = ((q0 + 15) >> 6) + 1;  // 64-key chunks

  // shuffle sources for P transform
  const int srcA = (quad & 1) * 32 + l15;
  const int srcB = srcA + 16;
  const bool hiTile = (quad >> 1) != 0;

  // K-frag loader: kf[ks*4+nt]
  auto loadK = [&](int c, bf16x8 (&kf)[8]) {
    const __bf16* kp = kp0 + (size_t)c * 64 * 64;
#pragma unroll
    for (int ks = 0; ks < 2; ks++)
#pragma unroll
      for (int nt = 0; nt < 4; nt++)
        kf[ks * 4 + nt] = *(const bf16x8*)(kp + (size_t)(nt * 16 + l15) * 64 +
                                           ks * 32 + quad * 8);
  };

  auto body = [&](int c, bf16x8 (&cur)[8], bf16x8 (&nxt)[8]) {
    int amv = amask[b * S + c * 64 + lane];  // issue early

    // V frags for this chunk: vf[s*4+nd]
    bf16x8 vf[8];
#pragma unroll
    for (int s = 0; s < 2; s++)
#pragma unroll
      for (int nd = 0; nd < 4; nd++)
        vf[s * 4 + nd] = *(const bf16x8*)(vp0 + c * 64 + s * 32 +
                                          (size_t)(nd * 16 + l15) * S + quad * 8);

    // S^T = K Q^T
    floatx4 st[4] = {};
#pragma unroll
    for (int ks = 0; ks < 2; ks++)
#pragma unroll
      for (int nt = 0; nt < 4; nt++)
        st[nt] = mfma16(cur[ks * 4 + nt], qf[ks], st[nt]);

    if (c + 1 < nch) loadK(c + 1, nxt);  // prefetch next K chunk

    unsigned long long pm = __ballot(amv == 0);

    // mask (before scale, like reference)
    if (c == nch - 1) {
#pragma unroll
      for (int nt = 0; nt < 4; nt++) {
        int kl = nt * 16 + quad * 4;
        int keyg = c * 64 + kl;
#pragma unroll
        for (int r = 0; r < 4; r++) {
          bool pad = (pm >> (kl + r)) & 1ull;
          float sv = st[nt][r] * 0.125f;
          bool masked = pad || (keyg + r > q0 + l15);
          st[nt][r] = masked ? -1.25e8f : sv;
        }
      }
    } else {
#pragma unroll
      for (int nt = 0; nt < 4; nt++) {
        int kl = nt * 16 + quad * 4;
#pragma unroll
        for (int r = 0; r < 4; r++) {
          bool pad = (pm >> (kl + r)) & 1ull;
          float sv = st[nt][r] * 0.125f;
          st[nt][r] = pad ? -1.25e8f : sv;
        }
      }
    }

    // online softmax (per q = l15), tree reductions
    float m4[4];
#pragma unroll
    for (int nt = 0; nt < 4; nt++)
      m4[nt] = fmaxf(fmaxf(st[nt][0], st[nt][1]), fmaxf(st[nt][2], st[nt][3]));
    float rm = fmaxf(fmaxf(m4[0], m4[1]), fmaxf(m4[2], m4[3]));
    rm = fmaxf(rm, __shfl_xor(rm, 16, 64));
    rm = fmaxf(rm, __shfl_xor(rm, 32, 64));
    float mnew = fmaxf(mrun, rm);
    float al = exp2f((mrun - mnew) * LOG2E);
    mrun = mnew;
    float s4[4];
#pragma unroll
    for (int nt = 0; nt < 4; nt++) {
      float p0 = exp2f((st[nt][0] - mnew) * LOG2E);
      float p1 = exp2f((st[nt][1] - mnew) * LOG2E);
      float p2 = exp2f((st[nt][2] - mnew) * LOG2E);
      float p3 = exp2f((st[nt][3] - mnew) * LOG2E);
      st[nt][0] = p0; st[nt][1] = p1; st[nt][2] = p2; st[nt][3] = p3;
      s4[nt] = (p0 + p1) + (p2 + p3);
    }
    float rs = (s4[0] + s4[1]) + (s4[2] + s4[3]);
    rs += __shfl_xor(rs, 16, 64);
    rs += __shfl_xor(rs, 32, 64);
    lrun = lrun * al + rs;

    // rescale O (alpha per O-row quad*4+r)
    float ar[4];
#pragma unroll
    for (int r = 0; r < 4; r++) ar[r] = __shfl(al, quad * 4 + r, 64);
#pragma unroll
    for (int nd = 0; nd < 4; nd++)
#pragma unroll
      for (int r = 0; r < 4; r++) oacc[nd][r] *= ar[r];

    // pack P and transform to A-layout via shuffles
    unsigned pkLo[4], pkHi[4];
#pragma unroll
    for (int nt = 0; nt < 4; nt++) {
      pkLo[nt] = pack_bf16(st[nt][0], st[nt][1]);
      pkHi[nt] = pack_bf16(st[nt][2], st[nt][3]);
    }
#pragma unroll
    for (int s = 0; s < 2; s++) {
      int t0 = s * 2, t1 = s * 2 + 1;
      unsigned u0a = __shfl((int)pkLo[t0], srcA, 64);
      unsigned u0b = __shfl((int)pkLo[t1], srcA, 64);
      unsigned u1a = __shfl((int)pkHi[t0], srcA, 64);
      unsigned u1b = __shfl((int)pkHi[t1], srcA, 64);
      unsigned u2a = __shfl((int)pkLo[t0], srcB, 64);
      unsigned u2b = __shfl((int)pkLo[t1], srcB, 64);
      unsigned u3a = __shfl((int)pkHi[t0], srcB, 64);
      unsigned u3b = __shfl((int)pkHi[t1], srcB, 64);
      unsigned u[4] = {hiTile ? u0b : u0a, hiTile ? u1b : u1a,
                       hiTile ? u2b : u2a, hiTile ? u3b : u3a};
      bf16x8 pf = *(bf16x8*)u;
#pragma unroll
      for (int nd = 0; nd < 4; nd++)
        oacc[nd] = mfma16(pf, vf[s * 4 + nd], oacc[nd]);
    }
  };

  bf16x8 kfA[8], kfB[8];
  loadK(0, kfA);
  int c = 0;
  while (true) {
    body(c, kfA, kfB);
    if (++c >= nch) break;
    body(c, kfB, kfA);
    if (++c >= nch) break;
  }

  // epilogue: ctx[b][s][h*64+dh] = O / l ;  O rows = quad*4+r
  float lr[4];
#pragma unroll
  for (int r = 0; r < 4; r++)
    lr[r] = 1.0f / __shfl(lrun, quad * 4 + r, 64);
#pragma unroll
  for (int nd = 0; nd < 4; nd++) {
#pragma unroll
    for (int r = 0; r < 4; r++) {
      int s = q0 + quad * 4 + r;
      int dh = nd * 16 + l15;
      ctx[((size_t)(b * 2048 + s)) * 1024 + h * 64 + dh] =
          (__bf16)(oacc[nd][r] * lr[r]);
    }
  }
}

// ---------------------------------------------------------------------------
extern "C" void kernel_launch(void* const* d_in, const int* in_sizes, int n_in,
                              void* d_out, int out_size, void* d_ws, size_t ws_size,
                              hipStream_t stream) {
  const float* x  = (const float*)d_in[0];
  const int*   am = (const int*)d_in[1];
  const float* Wq = (const float*)d_in[2];
  const float* bq = (const float*)d_in[3];
  const float* Aq = (const float*)d_in[4];
  const float* Bq = (const float*)d_in[5];
  const float* Wp = (const float*)d_in[6];
  const float* bp = (const float*)d_in[7];
  const float* Ap = (const float*)d_in[8];
  const float* Bp = (const float*)d_in[9];

  __bf16* wqkvT = (__bf16*)d_ws;                       // [3072][1024]
  __bf16* wpT   = wqkvT + (size_t)3072 * 1024;         // [1024][1024]
  __bf16* xbf   = wpT   + (size_t)1024 * 1024;         // [4096][1024]
  __bf16* qbuf  = xbf   + (size_t)4096 * 1024;         // [2][16][2048][64] (+kbuf)
  __bf16* vtbuf = qbuf  + (size_t)2 * 4194304;         // [2][16][64][2048]
  __bf16* ctxb  = vtbuf + (size_t)4194304;             // [4096][1024]

  fold_wt<<<dim3(48, 16), 256, 0, stream>>>(Wq, Aq, Bq, wqkvT, 3072);
  fold_wt<<<dim3(16, 16), 256, 0, stream>>>(Wp, Ap, Bp, wpT, 1024);
  cast_x<<<4096, 256, 0, stream>>>(x, xbf);

  gemm_qkv<<<dim3(32, 24), 256, 0, stream>>>(wqkvT, xbf, bq, qbuf, vtbuf);
  flash_attn<<<4096, 64, 0, stream>>>(qbuf, qbuf + 4194304, vtbuf, am, ctxb);
  gemm_proj<<<dim3(8, 64), 256, 0, stream>>>(ctxb, wpT, bp, (float*)d_out, 1024);
}